// Round 9
// baseline (414.262 us; speedup 1.0000x reference)
//
#include <hip/hip_runtime.h>
#include <math.h>

#define NSRC 100000
#define NDST 100000
#define NE   1600000
#define IND  128
#define OUTD 64
#define SLOPE 0.01f
#define CSTR 16            // cnt stride: 16 ints = one 64B line per dst (r3 win)
#define NR   4             // src ranges (25000 each): pass-p z16 window = 3.2MB < 4MB L2/XCD
#define RNG  25000
#define SUBCAP 24          // per-range bucket cap: Poisson(4) tail, P(any overflow) ~ 4e-7
#define SLOTW (NR * SUBCAP)   // 96 ints per dst

#define FILL_BLOCKS 782    // r3 optimum (confirmed vs ILP-8 r2/r7, 2xTLP r5, interleave r6)
#define ER_BLOCKS   782
#define ZTILES      1563
#define P1_BLOCKS (FILL_BLOCKS + ER_BLOCKS + ZTILES)   // SLAB order (r6 lesson)

#define AGG_BLOCKS 2048
#define AGG_WAVES (AGG_BLOCKS * 4)
#define CHUNK ((NDST + AGG_WAVES - 1) / AGG_WAVES)   // 13 dsts per wave

#define ZERO_N (NDST * CSTR / 4)
#define ZERO_BLOCKS ((ZERO_N + 255) / 256)

typedef _Float16       f16x8 __attribute__((ext_vector_type(8)));
typedef float          f32x4 __attribute__((ext_vector_type(4)));

__device__ __forceinline__ float softplus_f(float x) {
    return (x > 20.f) ? x : log1pf(__expf(x));
}
__device__ __forceinline__ unsigned short f2bf(float f) {
    unsigned u = __float_as_uint(f);
    return (unsigned short)((u + 0x7FFFu + ((u >> 16) & 1u)) >> 16);
}
__device__ __forceinline__ float bf2f(unsigned short h) {
    return __uint_as_float(((unsigned)h) << 16);
}

// ---------------------------------------------------------------------------
// zsrc: 64-row tile, 4 waves x 16 rows, f16 MFMA 16x16x32, K=128, fp32 acc.
// (byte-identical to round 3 -- measured best, 3x confirmed)
__device__ __forceinline__ void zsrc_body(float* vsrc, int tile,
                                          const float* __restrict__ h_src,
                                          const float* __restrict__ W_src,
                                          const float* __restrict__ attn_w,
                                          int iu,
                                          unsigned short* __restrict__ z16,
                                          float* __restrict__ el) {
    const int t = threadIdx.x;
    if (t < IND) {
        float a = 0.f;
#pragma unroll 8
        for (int o = 0; o < OUTD; ++o)
            a = fmaf(W_src[o * IND + t], attn_w[o], a);
        vsrc[t] = a;
    }
    __syncthreads();

    const int w = t >> 6, l = t & 63;
    const int r = l & 15, q = l >> 4;
    const int rowA  = tile * 64 + w * 16 + r;
    const int rowAc = (rowA < NSRC) ? rowA : (NSRC - 1);

    f32x4 acc[4];
#pragma unroll
    for (int c = 0; c < 4; ++c) acc[c] = (f32x4)0.f;
    float elp = 0.f;

#pragma unroll
    for (int ks = 0; ks < 4; ++ks) {
        const float* ap = h_src + rowAc * IND + ks * 32 + q * 8;
        float4 a0 = *(const float4*)ap;
        float4 a1 = *(const float4*)(ap + 4);
        const float* vp = vsrc + ks * 32 + q * 8;
        float4 v0 = *(const float4*)vp;
        float4 v1 = *(const float4*)(vp + 4);
        elp = fmaf(a0.x, v0.x, elp); elp = fmaf(a0.y, v0.y, elp);
        elp = fmaf(a0.z, v0.z, elp); elp = fmaf(a0.w, v0.w, elp);
        elp = fmaf(a1.x, v1.x, elp); elp = fmaf(a1.y, v1.y, elp);
        elp = fmaf(a1.z, v1.z, elp); elp = fmaf(a1.w, v1.w, elp);
        f16x8 af;
        af[0] = (_Float16)a0.x; af[1] = (_Float16)a0.y;
        af[2] = (_Float16)a0.z; af[3] = (_Float16)a0.w;
        af[4] = (_Float16)a1.x; af[5] = (_Float16)a1.y;
        af[6] = (_Float16)a1.z; af[7] = (_Float16)a1.w;
#pragma unroll
        for (int c = 0; c < 4; ++c) {
            const float* bp = W_src + (16 * c + r) * IND + ks * 32 + q * 8;
            float4 b0 = *(const float4*)bp;
            float4 b1 = *(const float4*)(bp + 4);
            f16x8 bf;
            bf[0] = (_Float16)b0.x; bf[1] = (_Float16)b0.y;
            bf[2] = (_Float16)b0.z; bf[3] = (_Float16)b0.w;
            bf[4] = (_Float16)b1.x; bf[5] = (_Float16)b1.y;
            bf[6] = (_Float16)b1.z; bf[7] = (_Float16)b1.w;
            acc[c] = __builtin_amdgcn_mfma_f32_16x16x32_f16(af, bf, acc[c], 0, 0, 0);
        }
    }

    if (!iu) {
        elp += __shfl_xor(elp, 16);
        elp += __shfl_xor(elp, 32);
        if (q == 0 && rowA < NSRC) el[rowA] = elp;
    } else {
#pragma unroll
        for (int c = 0; c < 4; ++c)
#pragma unroll
            for (int j = 0; j < 4; ++j) acc[c][j] = softplus_f(acc[c][j]);
        float ac0 = attn_w[r], ac1 = attn_w[16 + r], ac2 = attn_w[32 + r], ac3 = attn_w[48 + r];
#pragma unroll
        for (int j = 0; j < 4; ++j) {
            float s = fmaf(acc[0][j], ac0, fmaf(acc[1][j], ac1,
                      fmaf(acc[2][j], ac2, acc[3][j] * ac3)));
            s += __shfl_xor(s, 1); s += __shfl_xor(s, 2);
            s += __shfl_xor(s, 4); s += __shfl_xor(s, 8);
            const int row = tile * 64 + w * 16 + q * 4 + j;
            if (r == 0 && row < NSRC) el[row] = s;
        }
    }

    const int rowD0 = tile * 64 + w * 16 + q * 4;
#pragma unroll
    for (int j = 0; j < 4; ++j) {
        const int row = rowD0 + j;
        if (row < NSRC) {
#pragma unroll
            for (int c = 0; c < 4; ++c)
                z16[row * OUTD + 16 * c + r] = f2bf(acc[c][j]);
        }
    }
}

// ---------------------------------------------------------------------------
// er: (byte-identical to round 3)
__device__ __forceinline__ void er_body(float* v, int eb,
                                        const float* __restrict__ h_dst,
                                        const float* __restrict__ W_dst,
                                        const float* __restrict__ attn_w,
                                        float* __restrict__ er) {
    const int t = threadIdx.x;
    if (t < IND) {
        float a = 0.f;
#pragma unroll 8
        for (int o = 0; o < OUTD; ++o)
            a = fmaf(W_dst[o * IND + t], attn_w[OUTD + o], a);
        v[t] = a;
    }
    __syncthreads();
    const int wv = t >> 6, l = t & 63, hh = l >> 5, c = l & 31;
    float4 vv = *(const float4*)(v + c * 4);
    const int row0 = eb * 128;
#pragma unroll 4
    for (int p = 0; p < 16; ++p) {
        int row = row0 + p * 8 + wv * 2 + hh;
        if (row < NDST) {
            float4 x = *(const float4*)(h_dst + row * IND + c * 4);
            float s = fmaf(x.x, vv.x, fmaf(x.y, vv.y, fmaf(x.z, vv.z, x.w * vv.w)));
            s += __shfl_xor(s, 16); s += __shfl_xor(s, 8);
            s += __shfl_xor(s, 4);  s += __shfl_xor(s, 2);
            s += __shfl_xor(s, 1);
            if (c == 0) er[row] = s;
        }
    }
}

// ---------------------------------------------------------------------------
// fill: r3 pacing (strided, unroll 2); the ONLY change is sub-bucketing by
// src range. Sub-counters live in the same 64B line per dst -> identical
// line-level contention (16 ops/line) as r3.
__device__ __forceinline__ void fill_body(int fb, const int* __restrict__ src,
                                          const int* __restrict__ dst,
                                          int* __restrict__ cnt,
                                          int* __restrict__ slot) {
    int j = fb * 2048 + threadIdx.x;
#pragma unroll 2
    for (int it = 0; it < 8; ++it, j += 256) {
        if (j < NE) {
            int d = dst[j];
            int s = src[j];
            int sub = s / RNG;                  // 0..3 (compiler magic-mul)
            int p = atomicAdd(&cnt[d * CSTR + sub], 1);
            if (p < SUBCAP) slot[d * SLOTW + sub * SUBCAP + p] = s;
        }
    }
}

// ---------------------------------------------------------------------------
__global__ __launch_bounds__(256) void k_p1(
        const float* __restrict__ h_src, const float* __restrict__ W_src,
        const float* __restrict__ attn_w, const int* __restrict__ item_user,
        const float* __restrict__ h_dst, const float* __restrict__ W_dst,
        const int* __restrict__ src_idx, const int* __restrict__ dst_idx,
        unsigned short* __restrict__ z16, float* __restrict__ el,
        float* __restrict__ er, int* __restrict__ cnt,
        int* __restrict__ slot) {
    __shared__ float smem[IND];
    const int b = blockIdx.x;
    if (b < FILL_BLOCKS) {
        fill_body(b, src_idx, dst_idx, cnt, slot);
    } else if (b < FILL_BLOCKS + ER_BLOCKS) {
        er_body(smem, b - FILL_BLOCKS, h_dst, W_dst, attn_w, er);
    } else {
        zsrc_body(smem, b - FILL_BLOCKS - ER_BLOCKS, h_src, W_src, attn_w,
                  *item_user, z16, el);
    }
}

// ---------------------------------------------------------------------------
__global__ __launch_bounds__(256) void k_zero(int4* __restrict__ p) {
    const int i = blockIdx.x * 256 + threadIdx.x;
    if (i < ZERO_N) p[i] = int4{0, 0, 0, 0};
}

// ---------------------------------------------------------------------------
// Windowed aggregate: OUTER pass loop over 4 src-ranges. During pass p every
// wave gathers z16 only within a 3.2MB window -> L2-resident per XCD;
// compulsory L3 traffic halves (205 -> ~102MB). Inner structure is
// edge-serial / dim-parallel (lane = output dim): one 128B wave read per
// edge, NO cross-group reduction. Partial sums RMW into out across passes;
// per-dst denom accumulates in lane-i of dsumC; pass 3 normalizes.
__global__ __launch_bounds__(256) void k_aggregate(
        const int* __restrict__ cnt, const int* __restrict__ slot,
        const float* __restrict__ el, const float* __restrict__ er,
        const unsigned short* __restrict__ z16, float* __restrict__ out) {
    const int wid  = blockIdx.x * 4 + (threadIdx.x >> 6);
    const int lane = threadIdx.x & 63;
    const int d0 = wid * CHUNK;
    if (d0 >= NDST) return;
    const int n = min(NDST - d0, CHUNK);

    // chunk metadata: 52 sub-counters (13 dst x 4 ranges) + 13 er, one gather each
    int cnL = 0;
    {
        const int i = lane >> 2, sub = lane & 3;
        if (lane < 4 * CHUNK && i < n) cnL = cnt[(d0 + i) * CSTR + sub];
    }
    float erL = (lane < n) ? er[d0 + lane] : 0.f;
    float dsumC = 0.f;                     // lane i accumulates dst i's denom

#pragma unroll
    for (int p = 0; p < NR; ++p) {
        for (int i = 0; i < n; ++i) {
            const int d = d0 + i;
            int sd = __shfl(cnL, i * 4 + p);
            sd = (sd < 0) ? 0 : ((sd > SUBCAP) ? SUBCAP : sd);

            int s = 0;
            if (lane < SUBCAP) s = slot[d * SLOTW + p * SUBCAP + lane];
            s = ((unsigned)s < (unsigned)NSRC) ? s : 0;

            const float er_d = __shfl(erL, i);
            float ex = 0.f;
            if (lane < sd) {               // masked gather (r2 lesson)
                float e = el[s] + er_d;
                e = (e > 0.f) ? e : SLOPE * e;
                ex = __expf(e);
            }
            float ds = ex;
#pragma unroll
            for (int off = 1; off < 64; off <<= 1) ds += __shfl_xor(ds, off);
            if (lane == i) dsumC += ds;

            float acc = 0.f;
#pragma unroll 4
            for (int e = 0; e < sd; ++e) {
                const int   se  = __shfl(s, e);
                const float exe = __shfl(ex, e);
                acc = fmaf(exe, bf2f(z16[se * OUTD + lane]), acc);
            }

            float* po = out + d * OUTD + lane;
            if (p == 0) {
                *po = acc;
            } else if (p < NR - 1) {
                *po += acc;
            } else {
                const float tot = __shfl(dsumC, i);
                const float inv = (tot > 0.f) ? 1.f / tot : 0.f;
                *po = (*po + acc) * inv;
            }
        }
    }
}

// ---------------------------------------------------------------------------
extern "C" void kernel_launch(void* const* d_in, const int* in_sizes, int n_in,
                              void* d_out, int out_size, void* d_ws, size_t ws_size,
                              hipStream_t stream) {
    const float* h_src   = (const float*)d_in[0];
    const float* h_dst   = (const float*)d_in[1];
    const int*   src_idx = (const int*)d_in[2];
    const int*   dst_idx = (const int*)d_in[3];
    const float* W_src   = (const float*)d_in[4];
    const float* W_dst   = (const float*)d_in[5];
    const float* attn_w  = (const float*)d_in[6];
    const int*   item_u  = (const int*)d_in[7];
    float* out = (float*)d_out;

    // workspace layout (bytes), NO aliasing:
    char* ws = (char*)d_ws;
    unsigned short* z16 = (unsigned short*)(ws);   // 12,800,000
    float* el   = (float*)(ws + 12800000);         //    400,000
    float* er   = (float*)(ws + 13200000);         //    400,000
    int*   cnt  = (int*)  (ws + 13600000);         //  6,400,000 (NDST*CSTR*4)
    int*   slot = (int*)  (ws + 20000000);         // 38,400,000 (NDST*SLOTW*4)
    // total 58.4 MB

    k_zero     <<<ZERO_BLOCKS, 256, 0, stream>>>((int4*)cnt);
    k_p1       <<<P1_BLOCKS,   256, 0, stream>>>(h_src, W_src, attn_w, item_u,
                                                 h_dst, W_dst, src_idx, dst_idx,
                                                 z16, el, er, cnt, slot);
    k_aggregate<<<AGG_BLOCKS,  256, 0, stream>>>(cnt, slot, el, er, z16, out);
}

// Round 10
// 381.375 us; speedup vs baseline: 1.0862x; 1.0862x over previous
//
#include <hip/hip_runtime.h>
#include <math.h>

#define NSRC 100000
#define NDST 100000
#define NE   1600000
#define IND  128
#define OUTD 64
#define SLOPE 0.01f
#define CSTR 16            // cnt stride: 16 ints = one 64B line per dst (r3 win)
#define NR   4             // src ranges (25000 each): pass-p z16 window = 3.2MB < 4MB L2/XCD
#define RNG  25000
#define SUBCAP 24          // per-range cap: Poisson(4) tail; r9 validated (passed, no overflow)
#define SLOTW (NR * SUBCAP)   // 96 ints per dst

#define FILL_BLOCKS 782    // r3 optimum (confirmed vs ILP-8 r2/r7, 2xTLP r5, interleave r6)
#define ER_BLOCKS   782
#define ZTILES      1563
#define P1_BLOCKS (FILL_BLOCKS + ER_BLOCKS + ZTILES)   // SLAB order (r6 lesson)

#define AGG_BLOCKS 2048
#define AGG_WAVES (AGG_BLOCKS * 4)
#define CHUNK ((NDST + AGG_WAVES - 1) / AGG_WAVES)   // 13 dsts per wave

#define ZERO_N (NDST * CSTR / 4)
#define ZERO_BLOCKS ((ZERO_N + 255) / 256)

typedef _Float16       f16x8 __attribute__((ext_vector_type(8)));
typedef float          f32x4 __attribute__((ext_vector_type(4)));

__device__ __forceinline__ float softplus_f(float x) {
    return (x > 20.f) ? x : log1pf(__expf(x));
}
__device__ __forceinline__ unsigned short f2bf(float f) {
    unsigned u = __float_as_uint(f);
    return (unsigned short)((u + 0x7FFFu + ((u >> 16) & 1u)) >> 16);
}
__device__ __forceinline__ float bf2f(unsigned short h) {
    return __uint_as_float(((unsigned)h) << 16);
}

// ---------------------------------------------------------------------------
// zsrc: 64-row tile, 4 waves x 16 rows, f16 MFMA 16x16x32, K=128, fp32 acc.
// (byte-identical to round 3 -- measured best, 3x confirmed)
__device__ __forceinline__ void zsrc_body(float* vsrc, int tile,
                                          const float* __restrict__ h_src,
                                          const float* __restrict__ W_src,
                                          const float* __restrict__ attn_w,
                                          int iu,
                                          unsigned short* __restrict__ z16,
                                          float* __restrict__ el) {
    const int t = threadIdx.x;
    if (t < IND) {
        float a = 0.f;
#pragma unroll 8
        for (int o = 0; o < OUTD; ++o)
            a = fmaf(W_src[o * IND + t], attn_w[o], a);
        vsrc[t] = a;
    }
    __syncthreads();

    const int w = t >> 6, l = t & 63;
    const int r = l & 15, q = l >> 4;
    const int rowA  = tile * 64 + w * 16 + r;
    const int rowAc = (rowA < NSRC) ? rowA : (NSRC - 1);

    f32x4 acc[4];
#pragma unroll
    for (int c = 0; c < 4; ++c) acc[c] = (f32x4)0.f;
    float elp = 0.f;

#pragma unroll
    for (int ks = 0; ks < 4; ++ks) {
        const float* ap = h_src + rowAc * IND + ks * 32 + q * 8;
        float4 a0 = *(const float4*)ap;
        float4 a1 = *(const float4*)(ap + 4);
        const float* vp = vsrc + ks * 32 + q * 8;
        float4 v0 = *(const float4*)vp;
        float4 v1 = *(const float4*)(vp + 4);
        elp = fmaf(a0.x, v0.x, elp); elp = fmaf(a0.y, v0.y, elp);
        elp = fmaf(a0.z, v0.z, elp); elp = fmaf(a0.w, v0.w, elp);
        elp = fmaf(a1.x, v1.x, elp); elp = fmaf(a1.y, v1.y, elp);
        elp = fmaf(a1.z, v1.z, elp); elp = fmaf(a1.w, v1.w, elp);
        f16x8 af;
        af[0] = (_Float16)a0.x; af[1] = (_Float16)a0.y;
        af[2] = (_Float16)a0.z; af[3] = (_Float16)a0.w;
        af[4] = (_Float16)a1.x; af[5] = (_Float16)a1.y;
        af[6] = (_Float16)a1.z; af[7] = (_Float16)a1.w;
#pragma unroll
        for (int c = 0; c < 4; ++c) {
            const float* bp = W_src + (16 * c + r) * IND + ks * 32 + q * 8;
            float4 b0 = *(const float4*)bp;
            float4 b1 = *(const float4*)(bp + 4);
            f16x8 bf;
            bf[0] = (_Float16)b0.x; bf[1] = (_Float16)b0.y;
            bf[2] = (_Float16)b0.z; bf[3] = (_Float16)b0.w;
            bf[4] = (_Float16)b1.x; bf[5] = (_Float16)b1.y;
            bf[6] = (_Float16)b1.z; bf[7] = (_Float16)b1.w;
            acc[c] = __builtin_amdgcn_mfma_f32_16x16x32_f16(af, bf, acc[c], 0, 0, 0);
        }
    }

    if (!iu) {
        elp += __shfl_xor(elp, 16);
        elp += __shfl_xor(elp, 32);
        if (q == 0 && rowA < NSRC) el[rowA] = elp;
    } else {
#pragma unroll
        for (int c = 0; c < 4; ++c)
#pragma unroll
            for (int j = 0; j < 4; ++j) acc[c][j] = softplus_f(acc[c][j]);
        float ac0 = attn_w[r], ac1 = attn_w[16 + r], ac2 = attn_w[32 + r], ac3 = attn_w[48 + r];
#pragma unroll
        for (int j = 0; j < 4; ++j) {
            float s = fmaf(acc[0][j], ac0, fmaf(acc[1][j], ac1,
                      fmaf(acc[2][j], ac2, acc[3][j] * ac3)));
            s += __shfl_xor(s, 1); s += __shfl_xor(s, 2);
            s += __shfl_xor(s, 4); s += __shfl_xor(s, 8);
            const int row = tile * 64 + w * 16 + q * 4 + j;
            if (r == 0 && row < NSRC) el[row] = s;
        }
    }

    const int rowD0 = tile * 64 + w * 16 + q * 4;
#pragma unroll
    for (int j = 0; j < 4; ++j) {
        const int row = rowD0 + j;
        if (row < NSRC) {
#pragma unroll
            for (int c = 0; c < 4; ++c)
                z16[row * OUTD + 16 * c + r] = f2bf(acc[c][j]);
        }
    }
}

// ---------------------------------------------------------------------------
// er: (byte-identical to round 3)
__device__ __forceinline__ void er_body(float* v, int eb,
                                        const float* __restrict__ h_dst,
                                        const float* __restrict__ W_dst,
                                        const float* __restrict__ attn_w,
                                        float* __restrict__ er) {
    const int t = threadIdx.x;
    if (t < IND) {
        float a = 0.f;
#pragma unroll 8
        for (int o = 0; o < OUTD; ++o)
            a = fmaf(W_dst[o * IND + t], attn_w[OUTD + o], a);
        v[t] = a;
    }
    __syncthreads();
    const int wv = t >> 6, l = t & 63, hh = l >> 5, c = l & 31;
    float4 vv = *(const float4*)(v + c * 4);
    const int row0 = eb * 128;
#pragma unroll 4
    for (int p = 0; p < 16; ++p) {
        int row = row0 + p * 8 + wv * 2 + hh;
        if (row < NDST) {
            float4 x = *(const float4*)(h_dst + row * IND + c * 4);
            float s = fmaf(x.x, vv.x, fmaf(x.y, vv.y, fmaf(x.z, vv.z, x.w * vv.w)));
            s += __shfl_xor(s, 16); s += __shfl_xor(s, 8);
            s += __shfl_xor(s, 4);  s += __shfl_xor(s, 2);
            s += __shfl_xor(s, 1);
            if (c == 0) er[row] = s;
        }
    }
}

// ---------------------------------------------------------------------------
// fill: r3 pacing; sub-bucketing by src range (r9, correctness-validated).
// Sub-counters share one 64B line per dst -> identical contention to r3.
__device__ __forceinline__ void fill_body(int fb, const int* __restrict__ src,
                                          const int* __restrict__ dst,
                                          int* __restrict__ cnt,
                                          int* __restrict__ slot) {
    int j = fb * 2048 + threadIdx.x;
#pragma unroll 2
    for (int it = 0; it < 8; ++it, j += 256) {
        if (j < NE) {
            int d = dst[j];
            int s = src[j];
            int sub = s / RNG;                  // 0..3 (compiler magic-mul)
            int p = atomicAdd(&cnt[d * CSTR + sub], 1);
            if (p < SUBCAP) slot[d * SLOTW + sub * SUBCAP + p] = s;
        }
    }
}

// ---------------------------------------------------------------------------
__global__ __launch_bounds__(256) void k_p1(
        const float* __restrict__ h_src, const float* __restrict__ W_src,
        const float* __restrict__ attn_w, const int* __restrict__ item_user,
        const float* __restrict__ h_dst, const float* __restrict__ W_dst,
        const int* __restrict__ src_idx, const int* __restrict__ dst_idx,
        unsigned short* __restrict__ z16, float* __restrict__ el,
        float* __restrict__ er, int* __restrict__ cnt,
        int* __restrict__ slot) {
    __shared__ float smem[IND];
    const int b = blockIdx.x;
    if (b < FILL_BLOCKS) {
        fill_body(b, src_idx, dst_idx, cnt, slot);
    } else if (b < FILL_BLOCKS + ER_BLOCKS) {
        er_body(smem, b - FILL_BLOCKS, h_dst, W_dst, attn_w, er);
    } else {
        zsrc_body(smem, b - FILL_BLOCKS - ER_BLOCKS, h_src, W_src, attn_w,
                  *item_user, z16, el);
    }
}

// ---------------------------------------------------------------------------
__global__ __launch_bounds__(256) void k_zero(int4* __restrict__ p) {
    const int i = blockIdx.x * 256 + threadIdx.x;
    if (i < ZERO_N) p[i] = int4{0, 0, 0, 0};
}

// ---------------------------------------------------------------------------
// Windowed aggregate, REGISTER-accumulated (r9 fix): outer pass loop over 4
// src-ranges keeps the device phase-coherent in a 3.2MB z16 window
// (L2-resident per XCD); per-dst accumulator = 1 VGPR/dst (lane = out dim),
// dst loop fully unrolled for static acc[] indexing (rule #20). Out written
// ONCE at the end -> no inter-pass memory traffic (r9's 200MB RMW bug).
__global__ __launch_bounds__(256) void k_aggregate(
        const int* __restrict__ cnt, const int* __restrict__ slot,
        const float* __restrict__ el, const float* __restrict__ er,
        const unsigned short* __restrict__ z16, float* __restrict__ out) {
    const int wid  = blockIdx.x * 4 + (threadIdx.x >> 6);
    const int lane = threadIdx.x & 63;
    const int d0 = wid * CHUNK;
    if (d0 >= NDST) return;
    const int n = min(NDST - d0, CHUNK);

    // chunk metadata: 52 sub-counters (13 dst x 4 ranges) + 13 er, one gather each
    int cnL = 0;
    {
        const int i = lane >> 2, sub = lane & 3;
        if (lane < 4 * CHUNK && i < n) cnL = cnt[(d0 + i) * CSTR + sub];
    }
    float erL = (lane < n) ? er[d0 + lane] : 0.f;

    float acc[CHUNK];
#pragma unroll
    for (int i = 0; i < CHUNK; ++i) acc[i] = 0.f;
    float dsumC = 0.f;                     // lane i accumulates dst i's denom

    for (int p = 0; p < NR; ++p) {
#pragma unroll
        for (int i = 0; i < CHUNK; ++i) {
            if (i < n) {
                const int d = d0 + i;
                int sd = __shfl(cnL, i * 4 + p);
                sd = (sd < 0) ? 0 : ((sd > SUBCAP) ? SUBCAP : sd);

                int s = 0;
                if (lane < SUBCAP) s = slot[d * SLOTW + p * SUBCAP + lane];
                s = ((unsigned)s < (unsigned)NSRC) ? s : 0;

                const float er_d = __shfl(erL, i);
                float ex = 0.f;
                if (lane < sd) {           // masked gather (r2 lesson)
                    float e = el[s] + er_d;
                    e = (e > 0.f) ? e : SLOPE * e;
                    ex = __expf(e);
                }
                float ds = ex;
#pragma unroll
                for (int off = 1; off < 64; off <<= 1) ds += __shfl_xor(ds, off);
                if (lane == i) dsumC += ds;

                for (int e = 0; e < sd; ++e) {
                    const int   se  = __shfl(s, e);
                    const float exe = __shfl(ex, e);
                    // 128B contiguous wave read of one z16 row (2 transactions)
                    acc[i] = fmaf(exe, bf2f(z16[se * OUTD + lane]), acc[i]);
                }
            }
        }
    }

    // single out write per dst (coalesced 256B per dst)
#pragma unroll
    for (int i = 0; i < CHUNK; ++i) {
        if (i < n) {
            const float tot = __shfl(dsumC, i);
            const float inv = (tot > 0.f) ? 1.f / tot : 0.f;
            out[(d0 + i) * OUTD + lane] = acc[i] * inv;
        }
    }
}

// ---------------------------------------------------------------------------
extern "C" void kernel_launch(void* const* d_in, const int* in_sizes, int n_in,
                              void* d_out, int out_size, void* d_ws, size_t ws_size,
                              hipStream_t stream) {
    const float* h_src   = (const float*)d_in[0];
    const float* h_dst   = (const float*)d_in[1];
    const int*   src_idx = (const int*)d_in[2];
    const int*   dst_idx = (const int*)d_in[3];
    const float* W_src   = (const float*)d_in[4];
    const float* W_dst   = (const float*)d_in[5];
    const float* attn_w  = (const float*)d_in[6];
    const int*   item_u  = (const int*)d_in[7];
    float* out = (float*)d_out;

    // workspace layout (bytes), NO aliasing:
    char* ws = (char*)d_ws;
    unsigned short* z16 = (unsigned short*)(ws);   // 12,800,000
    float* el   = (float*)(ws + 12800000);         //    400,000
    float* er   = (float*)(ws + 13200000);         //    400,000
    int*   cnt  = (int*)  (ws + 13600000);         //  6,400,000 (NDST*CSTR*4)
    int*   slot = (int*)  (ws + 20000000);         // 38,400,000 (NDST*SLOTW*4)
    // total 58.4 MB

    k_zero     <<<ZERO_BLOCKS, 256, 0, stream>>>((int4*)cnt);
    k_p1       <<<P1_BLOCKS,   256, 0, stream>>>(h_src, W_src, attn_w, item_u,
                                                 h_dst, W_dst, src_idx, dst_idx,
                                                 z16, el, er, cnt, slot);
    k_aggregate<<<AGG_BLOCKS,  256, 0, stream>>>(cnt, slot, el, er, z16, out);
}